// Round 1
// baseline (143.089 us; speedup 1.0000x reference)
//
#include <hip/hip_runtime.h>
#include <hip/hip_bf16.h>
#include <stdint.h>
#include <stddef.h>

// MMD via single signed 2N x 2N RBF gram, lower triangle only.
// Round 10: r9 structure (fp8 MX-scaled MFMA 16x16x128, 64 KB full-tile double
// buffer, 1 barrier/tile) but 512 threads / 8 waves per block in a 4x2 wave
// grid (wave tile 32x64). Same LDS -> still 2 blocks/CU, but 16 waves/CU
// (4/SIMD) instead of 8: one wave's exp2-epilogue overlaps another's MFMAs.
// Per-wave regs halved (af 32, acc 32) so __launch_bounds__(512,4) holds
// VGPR <= 128. Loop-invariant staging + B-read offsets hoisted out of bc loop.

#define N_PTS   8192
#define DIM     256
#define TWO_N   16384
#define CSTRIDE 16

#define AS1 __attribute__((address_space(1)))
#define AS3 __attribute__((address_space(3)))

typedef __attribute__((ext_vector_type(4))) float f32x4;
typedef __attribute__((ext_vector_type(4))) int   i32x4;
typedef __attribute__((ext_vector_type(8))) int   i32x8;

// ---------------------------------------------------------------------------
// Prep: fp32 -> fp8 e4m3 (row-major) + c2-scaled fp32 row norms + zero output.
// n2[row] = c2 * |z_row|^2, c2 = -log2e/sigma (epilogue adds directly).
// ---------------------------------------------------------------------------
__global__ __launch_bounds__(256) void mmd_prep(const float* __restrict__ X,
                                                const float* __restrict__ Y,
                                                const int* __restrict__ sigmap,
                                                unsigned char* __restrict__ Zf8,
                                                float* __restrict__ n2,
                                                float* __restrict__ out) {
    if (blockIdx.x == 0 && threadIdx.x == 0) out[0] = 0.0f;

    const int wave = threadIdx.x >> 6;
    const int lane = threadIdx.x & 63;
    const int row  = blockIdx.x * 4 + wave;          // 0 .. TWO_N-1

    const float* src = (row < N_PTS) ? (X + (size_t)row * DIM)
                                     : (Y + (size_t)(row - N_PTS) * DIM);
    float4 v = ((const float4*)src)[lane];           // 64 lanes x 4 = 256

    float s = v.x * v.x + v.y * v.y + v.z * v.z + v.w * v.w;
#pragma unroll
    for (int off = 32; off; off >>= 1) s += __shfl_down(s, off, 64);
    if (lane == 0) {
        const float c2 = -1.4426950408889634f / (float)(*sigmap);
        n2[row] = c2 * s;
    }

    const int p01 = __builtin_amdgcn_cvt_pk_fp8_f32(v.x, v.y, 0, false);
    const int p23 = __builtin_amdgcn_cvt_pk_fp8_f32(v.z, v.w, 0, false);
    const unsigned int pk = ((unsigned)p01 & 0xffffu) | ((unsigned)p23 << 16);
    *(unsigned int*)(Zf8 + (size_t)row * DIM + (size_t)lane * 4) = pk;
}

// ---------------------------------------------------------------------------
// Main. grid = 128*16; br = 127 - (bid>>4) (heavy first), cc = bid & 15;
// empty blocks (cc > br) exit. 8 waves in 4x2; wave (wm,wn) owns 32x64 =
// 2x4 MFMA tiles of 16x16x128 MX-fp8 (2 k-chunks of K=128 each).
// A frags (full K=256, 32 VGPRs) stationary; B tiles (32 KB) double-buffered.
// Operand layout (K=128): lane (g=lane>>4, ml=lane&15) holds row/col ml,
// k = [kc*128 + g*32, +32) -> 32 contiguous bytes = i32x8.
// ---------------------------------------------------------------------------
__global__ __launch_bounds__(512, 4) void mmd_main(const unsigned char* __restrict__ Zf8,
                                                   const float* __restrict__ n2,
                                                   const int* __restrict__ sigmap,
                                                   float* __restrict__ out) {
    __shared__ char smem_b[65536];   // 2 x 32 KB B-tile buffers, 16B-slot XOR swizzle
    __shared__ float wsum[8];

    const int bid = (int)blockIdx.x;
    const int br  = 127 - (bid >> 4);
    const int cc  = bid & 15;
    if (cc > br) return;

    const int t    = threadIdx.x;
    const int wave = t >> 6;
    const int lane = t & 63;
    const int wm   = wave >> 1;      // 0..3: 32-row group
    const int wn   = wave & 1;       // 0..1: 64-col group
    const int g    = lane >> 4;      // k-quad
    const int ml   = lane & 15;
    const int rowBase = br * 128;

    const float m2 = 2.8853900817779268f / (float)(*sigmap);   // -2*c2
    const int   SC = 0x7f7f7f7f;     // E8M0 unit scales (2^0) for all blocks

    // ---- loop-invariant staging offsets (2048 16B chunks / 512 threads) ----
    int goff[4], loff[4];
#pragma unroll
    for (int i = 0; i < 4; ++i) {
        const int cidx = i * 512 + t;            // 0..2047
        const int col  = cidx >> 4;              // col 0..127
        const int s    = cidx & 15;              // LDS slot within col
        const int gc   = s ^ (col & 15);         // XOR swizzle on source chunk
        goff[i] = col * 256 + gc * 16;           // byte offset within col-block
        loff[i] = cidx * 16;                     // linear LDS offset
    }

    // ---- stage B tile 0 into buffer 0 (overlaps A-frag loads below) ----
    {
        const size_t cb0 = (size_t)cc * 128 * 256;
#pragma unroll
        for (int i = 0; i < 4; ++i)
            __builtin_amdgcn_global_load_lds((const AS1 void*)(Zf8 + cb0 + goff[i]),
                                             (AS3 void*)(smem_b + loff[i]), 16, 0, 0);
    }

    // ---- A fragments (full K, this wave's 32 rows): 32 VGPRs ----
    i32x8 af[2][2];
#pragma unroll
    for (int mt = 0; mt < 2; ++mt) {
        const unsigned char* rp =
            Zf8 + (size_t)(rowBase + wm * 32 + mt * 16 + ml) * DIM + g * 32;
#pragma unroll
        for (int kc = 0; kc < 2; ++kc) {
            union { i32x4 h[2]; i32x8 v; } u;
            u.h[0] = *(const i32x4*)(rp + kc * 128);
            u.h[1] = *(const i32x4*)(rp + kc * 128 + 16);
            af[mt][kc] = u.v;
        }
    }
    // row-norm coefficients (c2-scaled) for this lane's 8 C rows
    float a_i[2][4];
#pragma unroll
    for (int mt = 0; mt < 2; ++mt)
#pragma unroll
        for (int rr = 0; rr < 4; ++rr)
            a_i[mt][rr] = n2[rowBase + wm * 32 + mt * 16 + g * 4 + rr];

    // ---- loop-invariant B-frag byte offsets (2nd 16B half is ^16) ----
    int boff[2][4];
#pragma unroll
    for (int kc = 0; kc < 2; ++kc)
#pragma unroll
        for (int nt = 0; nt < 4; ++nt) {
            const int col = wn * 64 + nt * 16 + ml;
            const int j0  = kc * 8 + g * 2;      // first 16B chunk of lane's 32B
            boff[kc][nt]  = col * 256 + ((j0 ^ ml) * 16);
        }

    float block_acc = 0.0f;
    const int brX = (br < 64);
    int cur = 0;

    for (int bc = cc; bc <= br; bc += CSTRIDE) {
        float b_j[4];
#pragma unroll
        for (int nt = 0; nt < 4; ++nt)
            b_j[nt] = n2[bc * 128 + wn * 64 + nt * 16 + ml];

        f32x4 acc[2][4] = {};

        __syncthreads();             // current buffer staged; other buffer free

        // ---- stage NEXT tile into the other buffer (overlaps compute) ----
        if (bc + CSTRIDE <= br) {
            const size_t cbN = (size_t)(bc + CSTRIDE) * 128 * 256;
            char* dst = smem_b + (cur ^ 1) * 32768;
#pragma unroll
            for (int i = 0; i < 4; ++i)
                __builtin_amdgcn_global_load_lds((const AS1 void*)(Zf8 + cbN + goff[i]),
                                                 (AS3 void*)(dst + loff[i]), 16, 0, 0);
        }

        // ---- compute: 2 k-chunks of K=128 ----
        const char* buf = smem_b + cur * 32768;
#pragma unroll
        for (int kc = 0; kc < 2; ++kc) {
            i32x8 bf[4];
#pragma unroll
            for (int nt = 0; nt < 4; ++nt) {
                union { i32x4 h[2]; i32x8 v; } u;
                u.h[0] = *(const i32x4*)(buf + boff[kc][nt]);
                u.h[1] = *(const i32x4*)(buf + (boff[kc][nt] ^ 16));
                bf[nt] = u.v;
            }
#pragma unroll
            for (int mt = 0; mt < 2; ++mt)
#pragma unroll
                for (int nt = 0; nt < 4; ++nt)
                    acc[mt][nt] = __builtin_amdgcn_mfma_scale_f32_16x16x128_f8f6f4(
                        af[mt][kc], bf[nt], acc[mt][nt],
                        0, 0,              // cbsz: fp8 A, blgp: fp8 B
                        0, SC,             // scale A: opsel 0, unit scales
                        0, SC);            // scale B: opsel 0, unit scales
        }

        // ---- epilogue: 4 independent partial sums (break add chain) ----
        float ts0 = 0.0f, ts1 = 0.0f, ts2 = 0.0f, ts3 = 0.0f;
#pragma unroll
        for (int mt = 0; mt < 2; ++mt)
#pragma unroll
            for (int nt = 0; nt < 4; ++nt) {
                const float ab = b_j[nt];
                ts0 += __builtin_amdgcn_exp2f(fmaf(acc[mt][nt][0], m2, a_i[mt][0] + ab));
                ts1 += __builtin_amdgcn_exp2f(fmaf(acc[mt][nt][1], m2, a_i[mt][1] + ab));
                ts2 += __builtin_amdgcn_exp2f(fmaf(acc[mt][nt][2], m2, a_i[mt][2] + ab));
                ts3 += __builtin_amdgcn_exp2f(fmaf(acc[mt][nt][3], m2, a_i[mt][3] + ab));
            }
        const float tsum = (ts0 + ts1) + (ts2 + ts3);

        const float sgn = ((bc < 64) == brX) ? 1.0f : -1.0f;
        const float w   = (bc == br) ? sgn : 2.0f * sgn;   // symmetry weight
        block_acc = fmaf(w, tsum, block_acc);
        cur ^= 1;
    }

    // ---- block reduction + single atomic ----
    float s = block_acc;
#pragma unroll
    for (int off = 32; off; off >>= 1) s += __shfl_down(s, off, 64);
    if (lane == 0) wsum[wave] = s;
    __syncthreads();
    if (t == 0) {
        float r = 0.0f;
#pragma unroll
        for (int wv = 0; wv < 8; ++wv) r += wsum[wv];
        atomicAdd(out, r * (1.0f / 67108864.0f));
    }
}

// ---------------------------------------------------------------------------
extern "C" void kernel_launch(void* const* d_in, const int* in_sizes, int n_in,
                              void* d_out, int out_size, void* d_ws, size_t ws_size,
                              hipStream_t stream) {
    const float* X      = (const float*)d_in[0];
    const float* Y      = (const float*)d_in[1];
    const int*   sigmap = (const int*)d_in[2];
    float*       out    = (float*)d_out;

    unsigned char* Zf8 = (unsigned char*)d_ws;                        // 4 MB
    float*         n2  = (float*)((char*)d_ws + (size_t)TWO_N * DIM);

    mmd_prep<<<TWO_N / 4, 256, 0, stream>>>(X, Y, sigmap, Zf8, n2, out);
    mmd_main<<<128 * CSTRIDE, 512, 0, stream>>>(Zf8, n2, sigmap, out);
}

// Round 2
// 120.489 us; speedup vs baseline: 1.1876x; 1.1876x over previous
//
#include <hip/hip_runtime.h>
#include <hip/hip_bf16.h>
#include <stdint.h>
#include <stddef.h>

// MMD via single signed 2N x 2N RBF gram, lower triangle only.
// Round 11: revert to r9 geometry (256 thr, 4 waves 2x2, 64 KB dbuf, 2 blk/CU)
// — r10's 512-thread version spilled (VGPR 64, WRITE_SIZE 48 MB). New: within-
// wave software pipeline of the epilogue: nt-outer compute, epilogue(nt-1)
// issued after MFMA(nt) so exp2/fma VALU work fills the MFMA pipe's shadow.
// kc=0 MFMA uses a hoisted zero C operand (no 64-mov acc re-init per tile).
// Staging offsets (goff/loff) and B-frag offsets (boff) hoisted out of bc loop.

#define N_PTS   8192
#define DIM     256
#define TWO_N   16384
#define CSTRIDE 16

#define AS1 __attribute__((address_space(1)))
#define AS3 __attribute__((address_space(3)))

typedef __attribute__((ext_vector_type(4))) float f32x4;
typedef __attribute__((ext_vector_type(4))) int   i32x4;
typedef __attribute__((ext_vector_type(8))) int   i32x8;

// ---------------------------------------------------------------------------
// Prep: fp32 -> fp8 e4m3 (row-major) + c2-scaled fp32 row norms + zero output.
// n2[row] = c2 * |z_row|^2, c2 = -log2e/sigma (epilogue adds directly).
// ---------------------------------------------------------------------------
__global__ __launch_bounds__(256) void mmd_prep(const float* __restrict__ X,
                                                const float* __restrict__ Y,
                                                const int* __restrict__ sigmap,
                                                unsigned char* __restrict__ Zf8,
                                                float* __restrict__ n2,
                                                float* __restrict__ out) {
    if (blockIdx.x == 0 && threadIdx.x == 0) out[0] = 0.0f;

    const int wave = threadIdx.x >> 6;
    const int lane = threadIdx.x & 63;
    const int row  = blockIdx.x * 4 + wave;          // 0 .. TWO_N-1

    const float* src = (row < N_PTS) ? (X + (size_t)row * DIM)
                                     : (Y + (size_t)(row - N_PTS) * DIM);
    float4 v = ((const float4*)src)[lane];           // 64 lanes x 4 = 256

    float s = v.x * v.x + v.y * v.y + v.z * v.z + v.w * v.w;
#pragma unroll
    for (int off = 32; off; off >>= 1) s += __shfl_down(s, off, 64);
    if (lane == 0) {
        const float c2 = -1.4426950408889634f / (float)(*sigmap);
        n2[row] = c2 * s;
    }

    const int p01 = __builtin_amdgcn_cvt_pk_fp8_f32(v.x, v.y, 0, false);
    const int p23 = __builtin_amdgcn_cvt_pk_fp8_f32(v.z, v.w, 0, false);
    const unsigned int pk = ((unsigned)p01 & 0xffffu) | ((unsigned)p23 << 16);
    *(unsigned int*)(Zf8 + (size_t)row * DIM + (size_t)lane * 4) = pk;
}

// ---------------------------------------------------------------------------
// Main. grid = 128*16; br = 127 - (bid>>4) (heavy first), cc = bid & 15;
// empty blocks (cc > br) exit. 4 waves in 2x2; wave (wm,wn) owns 64x64 =
// 4x4 MFMA tiles of 16x16x128 MX-fp8 (2 k-chunks of K=128 each).
// A frags (full K=256, 64 VGPRs) stationary; B tiles (32 KB) double-buffered.
// Compute is nt-outer; epilogue(nt-1) overlaps MFMA(nt) within the wave.
// ---------------------------------------------------------------------------
__global__ __launch_bounds__(256, 2) void mmd_main(const unsigned char* __restrict__ Zf8,
                                                   const float* __restrict__ n2,
                                                   const int* __restrict__ sigmap,
                                                   float* __restrict__ out) {
    __shared__ char smem_b[65536];   // 2 x 32 KB B-tile buffers, 16B-slot XOR swizzle
    __shared__ float wsum[4];

    const int bid = (int)blockIdx.x;
    const int br  = 127 - (bid >> 4);
    const int cc  = bid & 15;
    if (cc > br) return;

    const int t    = threadIdx.x;
    const int wave = t >> 6;
    const int lane = t & 63;
    const int wm   = wave >> 1;
    const int wn   = wave & 1;
    const int g    = lane >> 4;      // k-quad
    const int ml   = lane & 15;
    const int rowBase = br * 128;

    const float m2 = 2.8853900817779268f / (float)(*sigmap);   // -2*c2
    const int   SC = 0x7f7f7f7f;     // E8M0 unit scales (2^0) for all blocks

    // ---- loop-invariant staging offsets (2048 16B chunks / 256 threads) ----
    int goff[8], loff[8];
#pragma unroll
    for (int i = 0; i < 8; ++i) {
        const int cidx = i * 256 + t;            // 0..2047
        const int col  = cidx >> 4;              // col 0..127
        const int s    = cidx & 15;              // LDS slot within col
        const int gc   = s ^ (col & 15);         // XOR swizzle on source chunk
        goff[i] = col * 256 + gc * 16;           // byte offset within col-block
        loff[i] = cidx * 16;                     // linear LDS offset
    }

    // ---- stage B tile 0 into buffer 0 (overlaps A-frag loads below) ----
    {
        const size_t cb0 = (size_t)cc * 128 * 256;
#pragma unroll
        for (int i = 0; i < 8; ++i)
            __builtin_amdgcn_global_load_lds((const AS1 void*)(Zf8 + cb0 + goff[i]),
                                             (AS3 void*)(smem_b + loff[i]), 16, 0, 0);
    }

    // ---- A fragments (full K, this wave's 64 rows): 64 VGPRs ----
    i32x8 af[4][2];
#pragma unroll
    for (int mt = 0; mt < 4; ++mt) {
        const unsigned char* rp =
            Zf8 + (size_t)(rowBase + wm * 64 + mt * 16 + ml) * DIM + g * 32;
#pragma unroll
        for (int kc = 0; kc < 2; ++kc) {
            union { i32x4 h[2]; i32x8 v; } u;
            u.h[0] = *(const i32x4*)(rp + kc * 128);
            u.h[1] = *(const i32x4*)(rp + kc * 128 + 16);
            af[mt][kc] = u.v;
        }
    }
    // row-norm coefficients (c2-scaled) for this lane's 16 C rows
    float a_i[4][4];
#pragma unroll
    for (int mt = 0; mt < 4; ++mt)
#pragma unroll
        for (int rr = 0; rr < 4; ++rr)
            a_i[mt][rr] = n2[rowBase + wm * 64 + mt * 16 + g * 4 + rr];

    // ---- loop-invariant B-frag byte offsets (2nd 16B half is ^16) ----
    int boff[2][4];
#pragma unroll
    for (int kc = 0; kc < 2; ++kc)
#pragma unroll
        for (int nt = 0; nt < 4; ++nt) {
            const int col = wn * 64 + nt * 16 + ml;
            const int j0  = kc * 8 + g * 2;      // first 16B chunk of lane's 32B
            boff[kc][nt]  = col * 256 + ((j0 ^ ml) * 16);
        }

    const f32x4 zacc = {0.0f, 0.0f, 0.0f, 0.0f};   // hoisted MFMA C for kc=0

    float block_acc = 0.0f;
    const int brX = (br < 64);
    int cur = 0;

#define EPI(n) do {                                                                  \
        const float ab = b_j[n];                                                     \
        _Pragma("unroll")                                                            \
        for (int mt = 0; mt < 4; ++mt) {                                             \
            ts0 += __builtin_amdgcn_exp2f(fmaf(acc[mt][n][0], m2, a_i[mt][0] + ab)); \
            ts1 += __builtin_amdgcn_exp2f(fmaf(acc[mt][n][1], m2, a_i[mt][1] + ab)); \
            ts2 += __builtin_amdgcn_exp2f(fmaf(acc[mt][n][2], m2, a_i[mt][2] + ab)); \
            ts3 += __builtin_amdgcn_exp2f(fmaf(acc[mt][n][3], m2, a_i[mt][3] + ab)); \
        }                                                                            \
    } while (0)

    for (int bc = cc; bc <= br; bc += CSTRIDE) {
        float b_j[4];
#pragma unroll
        for (int nt = 0; nt < 4; ++nt)
            b_j[nt] = n2[bc * 128 + wn * 64 + nt * 16 + ml];

        f32x4 acc[4][4];
        float ts0 = 0.0f, ts1 = 0.0f, ts2 = 0.0f, ts3 = 0.0f;

        __syncthreads();             // current buffer staged; other buffer free

        // ---- stage NEXT tile into the other buffer (overlaps compute) ----
        if (bc + CSTRIDE <= br) {
            const size_t cbN = (size_t)(bc + CSTRIDE) * 128 * 256;
            char* dst = smem_b + (cur ^ 1) * 32768;
#pragma unroll
            for (int i = 0; i < 8; ++i)
                __builtin_amdgcn_global_load_lds((const AS1 void*)(Zf8 + cbN + goff[i]),
                                                 (AS3 void*)(dst + loff[i]), 16, 0, 0);
        }

        // ---- compute: nt-outer, epilogue software-pipelined one nt behind ----
        const char* buf = smem_b + cur * 32768;
#pragma unroll
        for (int nt = 0; nt < 4; ++nt) {
            i32x8 bf[2];
#pragma unroll
            for (int kc = 0; kc < 2; ++kc) {
                union { i32x4 h[2]; i32x8 v; } u;
                u.h[0] = *(const i32x4*)(buf + boff[kc][nt]);
                u.h[1] = *(const i32x4*)(buf + (boff[kc][nt] ^ 16));
                bf[kc] = u.v;
            }
#pragma unroll
            for (int mt = 0; mt < 4; ++mt)
                acc[mt][nt] = __builtin_amdgcn_mfma_scale_f32_16x16x128_f8f6f4(
                    af[mt][0], bf[0], zacc, 0, 0, 0, SC, 0, SC);
#pragma unroll
            for (int mt = 0; mt < 4; ++mt)
                acc[mt][nt] = __builtin_amdgcn_mfma_scale_f32_16x16x128_f8f6f4(
                    af[mt][1], bf[1], acc[mt][nt], 0, 0, 0, SC, 0, SC);

            // exp2/fma stream for the PREVIOUS nt fills this nt's MFMA shadow
            if (nt > 0) { const int np = nt - 1; EPI(np); }
        }
        EPI(3);

        const float tsum = (ts0 + ts1) + (ts2 + ts3);
        const float sgn = ((bc < 64) == brX) ? 1.0f : -1.0f;
        const float w   = (bc == br) ? sgn : 2.0f * sgn;   // symmetry weight
        block_acc = fmaf(w, tsum, block_acc);
        cur ^= 1;
    }
#undef EPI

    // ---- block reduction + single atomic ----
    float s = block_acc;
#pragma unroll
    for (int off = 32; off; off >>= 1) s += __shfl_down(s, off, 64);
    if (lane == 0) wsum[wave] = s;
    __syncthreads();
    if (t == 0)
        atomicAdd(out, (wsum[0] + wsum[1] + wsum[2] + wsum[3]) * (1.0f / 67108864.0f));
}

// ---------------------------------------------------------------------------
extern "C" void kernel_launch(void* const* d_in, const int* in_sizes, int n_in,
                              void* d_out, int out_size, void* d_ws, size_t ws_size,
                              hipStream_t stream) {
    const float* X      = (const float*)d_in[0];
    const float* Y      = (const float*)d_in[1];
    const int*   sigmap = (const int*)d_in[2];
    float*       out    = (float*)d_out;

    unsigned char* Zf8 = (unsigned char*)d_ws;                        // 4 MB
    float*         n2  = (float*)((char*)d_ws + (size_t)TWO_N * DIM);

    mmd_prep<<<TWO_N / 4, 256, 0, stream>>>(X, Y, sigmap, Zf8, n2, out);
    mmd_main<<<128 * CSTRIDE, 256, 0, stream>>>(Zf8, n2, sigmap, out);
}